// Round 8
// baseline (341.741 us; speedup 1.0000x reference)
//
#include <hip/hip_runtime.h>
#include <math.h>

#define N_REL  8
#define IN_CH  16
#define HID_CH 32
#define OUT_CH 2

#define BIN_BITS  9
#define BIN_NODES 512                    // nodes per coarse bin
#define KPB       (BIN_NODES * N_REL)    // 4096 (node,rel) keys per bin
#define NCHUNK    192                    // partition chunks (blocks)

// float -> bf16 round-to-nearest-even
static __device__ __forceinline__ unsigned short f2b(float f) {
    unsigned int u = __float_as_uint(f);
    u = (u + 0x7FFFu + ((u >> 16) & 1u)) >> 16;
    return (unsigned short)u;
}
static __device__ __forceinline__ float b2f(unsigned short s) {
    return __uint_as_float(((unsigned int)s) << 16);
}

// ---------------------------------------------------------------------------
// B1a: per-chunk histogram over coarse bins (LDS), H[bin][chunk] (bin-major)
// ---------------------------------------------------------------------------
__global__ __launch_bounds__(256) void part_hist_kernel(const int* __restrict__ dst,
                                                        int* __restrict__ H,
                                                        int E, int nbins, int chunksz) {
    __shared__ int hist[256];
    int chunk = blockIdx.x;
    int e0 = chunk * chunksz;
    int e1 = e0 + chunksz; if (e1 > E) e1 = E;

    for (int i = threadIdx.x; i < nbins; i += 256) hist[i] = 0;
    __syncthreads();
    for (int e = e0 + threadIdx.x; e < e1; e += 256)
        atomicAdd(&hist[dst[e] >> BIN_BITS], 1);
    __syncthreads();
    for (int i = threadIdx.x; i < nbins; i += 256)
        H[i * NCHUNK + chunk] = hist[i];
}

// ---------------------------------------------------------------------------
// scan_a/b/c: exclusive scan of H[0..M2) in place
// ---------------------------------------------------------------------------
__global__ __launch_bounds__(1024) void scan_a_kernel(int* __restrict__ ptr,
                                                      int* __restrict__ blksum, int M) {
    int i = blockIdx.x * 1024 + threadIdx.x;
    int val = (i < M) ? ptr[i] : 0;
    int lane = threadIdx.x & 63;
    int wid  = threadIdx.x >> 6;

    int v = val;
#pragma unroll
    for (int off = 1; off < 64; off <<= 1) {
        int u = __shfl_up(v, off, 64);
        if (lane >= off) v += u;
    }

    __shared__ int wsum[16];
    if (lane == 63) wsum[wid] = v;
    __syncthreads();

    if (wid == 0) {
        int worig = (lane < 16) ? wsum[lane] : 0;
        int wv = worig;
#pragma unroll
        for (int off = 1; off < 16; off <<= 1) {
            int u = __shfl_up(wv, off, 64);
            if (lane >= off) wv += u;
        }
        if (lane < 16) wsum[lane] = wv - worig;
        if (lane == 15) blksum[blockIdx.x] = wv;
    }
    __syncthreads();

    if (i < M) ptr[i] = (v - val) + wsum[wid];
}

__global__ void scan_b_kernel(int* __restrict__ blksum, int nb) {
    int lane = threadIdx.x & 63;
    int run = 0;
    for (int base = 0; base < nb; base += 64) {
        int i = base + lane;
        int val = (i < nb) ? blksum[i] : 0;
        int v = val;
#pragma unroll
        for (int off = 1; off < 64; off <<= 1) {
            int u = __shfl_up(v, off, 64);
            if (lane >= off) v += u;
        }
        if (i < nb) blksum[i] = run + (v - val);
        run += __shfl(v, 63, 64);
    }
}

__global__ __launch_bounds__(1024) void scan_c_kernel(int* __restrict__ ptr,
                                                      const int* __restrict__ blksum, int M) {
    int i = blockIdx.x * 1024 + threadIdx.x;
    if (i < M) ptr[i] += blksum[blockIdx.x];
}

// ---------------------------------------------------------------------------
// B1b: partition — chunk-block writes packed records to per-(bin,chunk) runs.
// pack: (localdst<<20) | (rel<<17) | src   (src < 2^17, localdst < 512)
// ---------------------------------------------------------------------------
__global__ __launch_bounds__(256) void part_scatter_kernel(const int* __restrict__ src,
                                                           const int* __restrict__ dst,
                                                           const int* __restrict__ rel,
                                                           const int* __restrict__ Hs,
                                                           int* __restrict__ be,
                                                           int E, int nbins, int chunksz) {
    __shared__ int base[256];
    __shared__ int fil[256];
    int chunk = blockIdx.x;
    int e0 = chunk * chunksz;
    int e1 = e0 + chunksz; if (e1 > E) e1 = E;

    for (int i = threadIdx.x; i < nbins; i += 256) {
        base[i] = Hs[i * NCHUNK + chunk];
        fil[i]  = 0;
    }
    __syncthreads();

    for (int e = e0 + threadIdx.x; e < e1; e += 256) {
        int d = dst[e];
        int b = d >> BIN_BITS;
        int slot = base[b] + atomicAdd(&fil[b], 1);
        be[slot] = ((d & (BIN_NODES - 1)) << 20) | (rel[e] << 17) | src[e];
    }
}

// ---------------------------------------------------------------------------
// B2: one block per bin — LDS counting sort over 4096 keys -> ends[] + csr[].
// ---------------------------------------------------------------------------
__global__ __launch_bounds__(256) void bin_build_kernel(const int* __restrict__ be,
                                                        const int* __restrict__ Hs,
                                                        int* __restrict__ ends,
                                                        int* __restrict__ csr,
                                                        int E, int nbins) {
    int b  = blockIdx.x;
    int s0 = Hs[b * NCHUNK];
    int s1 = (b + 1 < nbins) ? Hs[(b + 1) * NCHUNK] : E;
    int t  = threadIdx.x;

    __shared__ int cnt[KPB];
    __shared__ int off[KPB];
    __shared__ int fil[KPB];
    __shared__ int ws[4];

    for (int i = t; i < KPB; i += 256) { cnt[i] = 0; fil[i] = 0; }
    __syncthreads();

    for (int p = s0 + t; p < s1; p += 256)
        atomicAdd(&cnt[be[p] >> 17], 1);          // key = (localdst<<3)|rel
    __syncthreads();

    int kbase = t * 16;
    int loc[16];
    int sum = 0;
#pragma unroll
    for (int i = 0; i < 16; ++i) { loc[i] = sum; sum += cnt[kbase + i]; }

    int lane = t & 63, wid = t >> 6;
    int v = sum;
#pragma unroll
    for (int o = 1; o < 64; o <<= 1) {
        int u = __shfl_up(v, o, 64);
        if (lane >= o) v += u;
    }
    if (lane == 63) ws[wid] = v;
    __syncthreads();
    int woff = 0;
    for (int i = 0; i < wid; ++i) woff += ws[i];
    int excl = woff + (v - sum);
#pragma unroll
    for (int i = 0; i < 16; ++i) off[kbase + i] = excl + loc[i];
    __syncthreads();

    for (int i = t; i < KPB; i += 256)
        ends[b * KPB + i] = s0 + off[i] + cnt[i];

    for (int p = s0 + t; p < s1; p += 256) {
        int pk = be[p];
        int k  = pk >> 17;
        int slot = s0 + off[k] + atomicAdd(&fil[k], 1);
        csr[slot] = pk & 0x1FFFF;
    }
}

// ---------------------------------------------------------------------------
// x16: bf16 copy of x ([N][16], 3.2 MB — per-XCD-L2-resident gather table)
// ---------------------------------------------------------------------------
__global__ __launch_bounds__(256) void x16_kernel(const float* __restrict__ x,
                                                  unsigned int* __restrict__ x16,
                                                  int n8) {
    int i = blockIdx.x * 256 + threadIdx.x;
    if (i >= n8) return;
    const float4* xp = (const float4*)x + i * 2;
    float4 a = xp[0], b = xp[1];
    uint4 o;
    o.x = ((unsigned)f2b(a.y) << 16) | f2b(a.x);
    o.y = ((unsigned)f2b(a.w) << 16) | f2b(a.z);
    o.z = ((unsigned)f2b(b.y) << 16) | f2b(b.x);
    o.w = ((unsigned)f2b(b.w) << 16) | f2b(b.z);
    ((uint4*)x16)[i] = o;
}

// ---------------------------------------------------------------------------
// l1: wave per node. Phase 1 (lane = f<16 x parity4): pure gather-sum of x16
// per (node,rel) segment -> scaled ss in LDS. Phase 2 (lane = rr<8, c=w*8+l/8):
// dense 144->32 transform, weights in registers, ss via 8-lane LDS broadcast,
// 3-shfl rr-reduce -> bf16 h16. No atomics, no big tables.
// ---------------------------------------------------------------------------
__global__ __launch_bounds__(256) void l1_kernel(const float* __restrict__ x,
                                                 const unsigned short* __restrict__ x16,
                                                 const int* __restrict__ csr,
                                                 const int* __restrict__ ends,
                                                 const float* __restrict__ W1,
                                                 const float* __restrict__ root1,
                                                 const float* __restrict__ b1,
                                                 unsigned short* __restrict__ h16, int N) {
    __shared__ float ss[4][N_REL * IN_CH];   // 2 KB: per-wave segment sums (scaled)
    __shared__ float xs[4][IN_CH];           // staged x rows for root term

    int t = threadIdx.x, w = t >> 6, l = t & 63;
    int node = blockIdx.x * 4 + w;

    // phase-2 constants (independent of node)
    int rr = l & 7;
    int c  = (w << 3) + (l >> 3);
    float wcol[IN_CH];
#pragma unroll
    for (int f = 0; f < IN_CH; ++f) wcol[f] = W1[(rr * IN_CH + f) * HID_CH + c];
    float r1a  = root1[(rr * 2) * HID_CH + c];
    float r1b  = root1[(rr * 2 + 1) * HID_CH + c];
    float bias = b1[c];

    // ---- phase 1: gather ----
    int f   = l & 15;
    int sub = l >> 4;      // 0..3 edge parity
    if (node < N) {
        int4 e0 = ((const int4*)ends)[node * 2];
        int4 e1 = ((const int4*)ends)[node * 2 + 1];
        int end_r[N_REL] = {e0.x, e0.y, e0.z, e0.w, e1.x, e1.y, e1.z, e1.w};
        int prev = (node > 0) ? __ldg(&ends[node * N_REL - 1]) : 0;

        if (sub == 0) xs[w][f] = x[(node << 4) + f];

        for (int r = 0; r < N_REL; ++r) {
            int end = end_r[r];
            int len = end - prev;
            float ax = 0.0f;
            for (int p = prev + sub; p < end; p += 4)
                ax += b2f(x16[(csr[p] << 4) + f]);
            ax += __shfl_xor(ax, 16, 64);
            ax += __shfl_xor(ax, 32, 64);
            float inv = (len > 0) ? 1.0f / (float)len : 0.0f;
            if (sub == 0) ss[w][r * 16 + f] = ax * inv;
            prev = end;
        }
    } else if (sub == 0) {
        xs[w][f] = 0.0f;
#pragma unroll
        for (int r = 0; r < N_REL; ++r) ss[w][r * 16 + f] = 0.0f;
    }
    __syncthreads();

    // ---- phase 2: transform 4 nodes ----
    int nb = blockIdx.x * 4;
#pragma unroll
    for (int j = 0; j < 4; ++j) {
        int n = nb + j;
        if (n >= N) break;
        float a = 0.0f;
#pragma unroll
        for (int ff = 0; ff < IN_CH; ++ff)
            a = fmaf(ss[j][rr * 16 + ff], wcol[ff], a);
        a = fmaf(xs[j][rr * 2], r1a, a);
        a = fmaf(xs[j][rr * 2 + 1], r1b, a);
        a += __shfl_xor(a, 1, 64);
        a += __shfl_xor(a, 2, 64);
        a += __shfl_xor(a, 4, 64);
        if (rr == 0)
            h16[(n << 5) + c] = f2b(fmaxf(a + bias, 0.0f));
    }
}

// ---------------------------------------------------------------------------
// l2 fused: wave per node, lane = (f<32, parity2). Per edge: one bf16 h16 row
// (64B line). Per segment: 2 FMA (defer f-reduction). One final 6-step shfl
// tree + log_softmax. W2/root2 entirely in registers.
// ---------------------------------------------------------------------------
__global__ __launch_bounds__(256) void l2_kernel(const unsigned short* __restrict__ h16,
                                                 const int* __restrict__ csr,
                                                 const int* __restrict__ ends,
                                                 const float* __restrict__ W2,
                                                 const float* __restrict__ root2,
                                                 const float* __restrict__ b2,
                                                 float* __restrict__ out, int N) {
    int t = threadIdx.x, l = t & 63;
    int node = (blockIdx.x * 256 + t) >> 6;
    int f   = l & 31;
    int sub = l >> 5;

    float2 w2r[N_REL];
#pragma unroll
    for (int r = 0; r < N_REL; ++r)
        w2r[r] = *(const float2*)(W2 + r * (HID_CH * OUT_CH) + f * 2);
    float2 rt = *(const float2*)(root2 + f * 2);

    if (node >= N) return;

    int4 e0 = ((const int4*)ends)[node * 2];
    int4 e1 = ((const int4*)ends)[node * 2 + 1];
    int end_r[N_REL] = {e0.x, e0.y, e0.z, e0.w, e1.x, e1.y, e1.z, e1.w};
    int prev = (node > 0) ? __ldg(&ends[node * N_REL - 1]) : 0;

    float o0 = 0.0f, o1 = 0.0f;
#pragma unroll
    for (int r = 0; r < N_REL; ++r) {
        int end = end_r[r];
        int len = end - prev;
        if (len > 0) {
            float hs = 0.0f;
            for (int p = prev + sub; p < end; p += 2)
                hs += b2f(h16[(csr[p] << 5) + f]);
            float s = hs * (1.0f / (float)len);
            o0 = fmaf(s, w2r[r].x, o0);
            o1 = fmaf(s, w2r[r].y, o1);
            prev = end;
        }
    }

    if (sub == 0) {   // root term counted once
        float hv = b2f(h16[(node << 5) + f]);
        o0 = fmaf(hv, rt.x, o0);
        o1 = fmaf(hv, rt.y, o1);
    }

#pragma unroll
    for (int m = 1; m < 64; m <<= 1) {
        o0 += __shfl_xor(o0, m, 64);
        o1 += __shfl_xor(o1, m, 64);
    }

    if (l == 0) {
        o0 += b2[0]; o1 += b2[1];
        float mx = fmaxf(o0, o1);
        float lg = mx + logf(__expf(o0 - mx) + __expf(o1 - mx));
        *(float2*)(out + ((long)node << 1)) = make_float2(o0 - lg, o1 - lg);
    }
}

// ---------------------------------------------------------------------------
extern "C" void kernel_launch(void* const* d_in, const int* in_sizes, int n_in,
                              void* d_out, int out_size, void* d_ws, size_t ws_size,
                              hipStream_t stream) {
    const float* x     = (const float*)d_in[0];
    const int*   eidx  = (const int*)d_in[1];
    const int*   etype = (const int*)d_in[2];
    const float* W1    = (const float*)d_in[3];
    const float* root1 = (const float*)d_in[4];
    const float* b1    = (const float*)d_in[5];
    const float* W2    = (const float*)d_in[6];
    const float* root2 = (const float*)d_in[7];
    const float* b2    = (const float*)d_in[8];
    float* out = (float*)d_out;

    const int N = in_sizes[0] / IN_CH;
    const int E = in_sizes[2];
    const int nbins   = (N + BIN_NODES - 1) >> BIN_BITS;
    const int chunksz = (E + NCHUNK - 1) / NCHUNK;
    const int M2      = nbins * NCHUNK;
    const int* src = eidx;
    const int* dst = eidx + E;

    char* wp = (char*)d_ws;
    auto take = [&](size_t bytes) {
        char* p = wp;
        wp += (bytes + 63) & ~(size_t)63;
        return p;
    };
    int*   H      = (int*)take((size_t)M2 * sizeof(int));
    int*   blksum = (int*)take(4096 * sizeof(int));
    int*   ends   = (int*)take((size_t)nbins * KPB * sizeof(int));
    int*   csr    = (int*)take((size_t)E * sizeof(int));
    unsigned short* x16 = (unsigned short*)take((size_t)N * IN_CH * sizeof(unsigned short));
    unsigned short* h16 = (unsigned short*)take((size_t)N * HID_CH * sizeof(unsigned short));
    int* be = (int*)take((size_t)E * sizeof(int));   // could alias h16, kept separate for safety

    const int B = 256;
    const int nb = (M2 + 1023) / 1024;

    x16_kernel<<<(N * 2 + B - 1) / B, B, 0, stream>>>(x, (unsigned int*)x16, N * 2);

    part_hist_kernel<<<NCHUNK, B, 0, stream>>>(dst, H, E, nbins, chunksz);
    scan_a_kernel<<<nb, 1024, 0, stream>>>(H, blksum, M2);
    scan_b_kernel<<<1, 64, 0, stream>>>(blksum, nb);
    scan_c_kernel<<<nb, 1024, 0, stream>>>(H, blksum, M2);
    part_scatter_kernel<<<NCHUNK, B, 0, stream>>>(src, dst, etype, H, be, E, nbins, chunksz);
    bin_build_kernel<<<nbins, B, 0, stream>>>(be, H, ends, csr, E, nbins);

    l1_kernel<<<(N + 3) / 4, B, 0, stream>>>(x, x16, csr, ends, W1, root1, b1, h16, N);
    l2_kernel<<<(N + 3) / 4, B, 0, stream>>>(h16, csr, ends, W2, root2, b2, out, N);
}

// Round 9
// 233.123 us; speedup vs baseline: 1.4659x; 1.4659x over previous
//
#include <hip/hip_runtime.h>
#include <math.h>

#define N_REL  8
#define IN_CH  16
#define HID_CH 32
#define OUT_CH 2

#define BIN_BITS  9
#define BIN_NODES 512                    // nodes per coarse bin
#define KPB       (BIN_NODES * N_REL)    // 4096 (node,rel) keys per bin
#define NCHUNK    192                    // partition chunks (blocks)

// float -> bf16 round-to-nearest-even
static __device__ __forceinline__ unsigned short f2b(float f) {
    unsigned int u = __float_as_uint(f);
    u = (u + 0x7FFFu + ((u >> 16) & 1u)) >> 16;
    return (unsigned short)u;
}
static __device__ __forceinline__ float b2f(unsigned short s) {
    return __uint_as_float(((unsigned int)s) << 16);
}

// ---------------------------------------------------------------------------
// B1a: per-chunk histogram over coarse bins (LDS), H[bin][chunk] (bin-major)
// ---------------------------------------------------------------------------
__global__ __launch_bounds__(256) void part_hist_kernel(const int* __restrict__ dst,
                                                        int* __restrict__ H,
                                                        int E, int nbins, int chunksz) {
    __shared__ int hist[256];
    int chunk = blockIdx.x;
    int e0 = chunk * chunksz;
    int e1 = e0 + chunksz; if (e1 > E) e1 = E;

    for (int i = threadIdx.x; i < nbins; i += 256) hist[i] = 0;
    __syncthreads();
    for (int e = e0 + threadIdx.x; e < e1; e += 256)
        atomicAdd(&hist[dst[e] >> BIN_BITS], 1);
    __syncthreads();
    for (int i = threadIdx.x; i < nbins; i += 256)
        H[i * NCHUNK + chunk] = hist[i];
}

// ---------------------------------------------------------------------------
// scan_a/b/c: exclusive scan of H[0..M2) in place
// ---------------------------------------------------------------------------
__global__ __launch_bounds__(1024) void scan_a_kernel(int* __restrict__ ptr,
                                                      int* __restrict__ blksum, int M) {
    int i = blockIdx.x * 1024 + threadIdx.x;
    int val = (i < M) ? ptr[i] : 0;
    int lane = threadIdx.x & 63;
    int wid  = threadIdx.x >> 6;

    int v = val;
#pragma unroll
    for (int off = 1; off < 64; off <<= 1) {
        int u = __shfl_up(v, off, 64);
        if (lane >= off) v += u;
    }

    __shared__ int wsum[16];
    if (lane == 63) wsum[wid] = v;
    __syncthreads();

    if (wid == 0) {
        int worig = (lane < 16) ? wsum[lane] : 0;
        int wv = worig;
#pragma unroll
        for (int off = 1; off < 16; off <<= 1) {
            int u = __shfl_up(wv, off, 64);
            if (lane >= off) wv += u;
        }
        if (lane < 16) wsum[lane] = wv - worig;
        if (lane == 15) blksum[blockIdx.x] = wv;
    }
    __syncthreads();

    if (i < M) ptr[i] = (v - val) + wsum[wid];
}

__global__ void scan_b_kernel(int* __restrict__ blksum, int nb) {
    int lane = threadIdx.x & 63;
    int run = 0;
    for (int base = 0; base < nb; base += 64) {
        int i = base + lane;
        int val = (i < nb) ? blksum[i] : 0;
        int v = val;
#pragma unroll
        for (int off = 1; off < 64; off <<= 1) {
            int u = __shfl_up(v, off, 64);
            if (lane >= off) v += u;
        }
        if (i < nb) blksum[i] = run + (v - val);
        run += __shfl(v, 63, 64);
    }
}

__global__ __launch_bounds__(1024) void scan_c_kernel(int* __restrict__ ptr,
                                                      const int* __restrict__ blksum, int M) {
    int i = blockIdx.x * 1024 + threadIdx.x;
    if (i < M) ptr[i] += blksum[blockIdx.x];
}

// ---------------------------------------------------------------------------
// B1b: partition — chunk-block writes packed records to per-(bin,chunk) runs.
// pack: (localdst<<20) | (rel<<17) | src   (src < 2^17, localdst < 512)
// ---------------------------------------------------------------------------
__global__ __launch_bounds__(256) void part_scatter_kernel(const int* __restrict__ src,
                                                           const int* __restrict__ dst,
                                                           const int* __restrict__ rel,
                                                           const int* __restrict__ Hs,
                                                           int* __restrict__ be,
                                                           int E, int nbins, int chunksz) {
    __shared__ int base[256];
    __shared__ int fil[256];
    int chunk = blockIdx.x;
    int e0 = chunk * chunksz;
    int e1 = e0 + chunksz; if (e1 > E) e1 = E;

    for (int i = threadIdx.x; i < nbins; i += 256) {
        base[i] = Hs[i * NCHUNK + chunk];
        fil[i]  = 0;
    }
    __syncthreads();

    for (int e = e0 + threadIdx.x; e < e1; e += 256) {
        int d = dst[e];
        int b = d >> BIN_BITS;
        int slot = base[b] + atomicAdd(&fil[b], 1);
        be[slot] = ((d & (BIN_NODES - 1)) << 20) | (rel[e] << 17) | src[e];
    }
}

// ---------------------------------------------------------------------------
// B2: one block per bin — LDS counting sort over 4096 keys -> ends[] + csr[].
// ---------------------------------------------------------------------------
__global__ __launch_bounds__(256) void bin_build_kernel(const int* __restrict__ be,
                                                        const int* __restrict__ Hs,
                                                        int* __restrict__ ends,
                                                        int* __restrict__ csr,
                                                        int E, int nbins) {
    int b  = blockIdx.x;
    int s0 = Hs[b * NCHUNK];
    int s1 = (b + 1 < nbins) ? Hs[(b + 1) * NCHUNK] : E;
    int t  = threadIdx.x;

    __shared__ int cnt[KPB];
    __shared__ int off[KPB];
    __shared__ int fil[KPB];
    __shared__ int ws[4];

    for (int i = t; i < KPB; i += 256) { cnt[i] = 0; fil[i] = 0; }
    __syncthreads();

    for (int p = s0 + t; p < s1; p += 256)
        atomicAdd(&cnt[be[p] >> 17], 1);          // key = (localdst<<3)|rel
    __syncthreads();

    int kbase = t * 16;
    int loc[16];
    int sum = 0;
#pragma unroll
    for (int i = 0; i < 16; ++i) { loc[i] = sum; sum += cnt[kbase + i]; }

    int lane = t & 63, wid = t >> 6;
    int v = sum;
#pragma unroll
    for (int o = 1; o < 64; o <<= 1) {
        int u = __shfl_up(v, o, 64);
        if (lane >= o) v += u;
    }
    if (lane == 63) ws[wid] = v;
    __syncthreads();
    int woff = 0;
    for (int i = 0; i < wid; ++i) woff += ws[i];
    int excl = woff + (v - sum);
#pragma unroll
    for (int i = 0; i < 16; ++i) off[kbase + i] = excl + loc[i];
    __syncthreads();

    for (int i = t; i < KPB; i += 256)
        ends[b * KPB + i] = s0 + off[i] + cnt[i];

    for (int p = s0 + t; p < s1; p += 256) {
        int pk = be[p];
        int k  = pk >> 17;
        int slot = s0 + off[k] + atomicAdd(&fil[k], 1);
        csr[slot] = pk & 0x1FFFF;
    }
}

// ---------------------------------------------------------------------------
// xw: xW16[n][r][c] = bf16( x[n] @ W1[r][:,c] )
// ---------------------------------------------------------------------------
#define XW_TILE 64
__global__ __launch_bounds__(256) void xw_kernel(const float* __restrict__ x,
                                                 const float* __restrict__ W1,
                                                 unsigned short* __restrict__ xW16, int N) {
    __shared__ float sx[XW_TILE * IN_CH];   // 4 KB
    int t = threadIdx.x;
    int node0 = blockIdx.x * XW_TILE;

    {
        int i4 = node0 * 4 + t;
        float4 v = make_float4(0.f, 0.f, 0.f, 0.f);
        if (i4 < N * 4) v = ((const float4*)x)[i4];
        ((float4*)sx)[t] = v;
    }
    __syncthreads();

    int r = t >> 5, c = t & 31;
    float w[IN_CH];
#pragma unroll
    for (int f = 0; f < IN_CH; ++f)
        w[f] = W1[(r * IN_CH + f) * HID_CH + c];

    int lim = N - node0; if (lim > XW_TILE) lim = XW_TILE;
    for (int ni = 0; ni < lim; ++ni) {
        const float4* xs = (const float4*)(sx + ni * IN_CH);
        float4 v0 = xs[0], v1 = xs[1], v2 = xs[2], v3 = xs[3];
        float a;
        a  = v0.x * w[0]  + v0.y * w[1]  + v0.z * w[2]  + v0.w * w[3];
        a += v1.x * w[4]  + v1.y * w[5]  + v1.z * w[6]  + v1.w * w[7];
        a += v2.x * w[8]  + v2.y * w[9]  + v2.z * w[10] + v2.w * w[11];
        a += v3.x * w[12] + v3.y * w[13] + v3.z * w[14] + v3.w * w[15];
        xW16[(node0 + ni) * (N_REL * HID_CH) + t] = f2b(a);
    }
}

// ---------------------------------------------------------------------------
// l1 gather: half-wave per node, lane = hidden channel c. 4-deep load pipeline.
// ---------------------------------------------------------------------------
__global__ __launch_bounds__(256) void l1_gather_kernel(const float* __restrict__ x,
                                                        const int* __restrict__ csr,
                                                        const int* __restrict__ ends,
                                                        const unsigned short* __restrict__ xW16,
                                                        const float* __restrict__ root1,
                                                        const float* __restrict__ b1,
                                                        float* __restrict__ h, int N) {
    int gid  = blockIdx.x * 256 + threadIdx.x;
    int node = gid >> 5;
    int c    = gid & 31;
    if (node >= N) return;

    int4 e0 = ((const int4*)ends)[node * 2];
    int4 e1 = ((const int4*)ends)[node * 2 + 1];
    int end_r[N_REL] = {e0.x, e0.y, e0.z, e0.w, e1.x, e1.y, e1.z, e1.w};

    int prev = (node > 0) ? __ldg(&ends[node * N_REL - 1]) : 0;
    float acc = 0.0f;

#pragma unroll
    for (int r = 0; r < N_REL; ++r) {
        int end = end_r[r];
        int len = end - prev;
        if (len > 0) {
            float seg = 0.0f;
            int p = prev;
            for (; p + 3 < end; p += 4) {       // 4 independent loads in flight
                int s0 = csr[p], s1 = csr[p + 1], s2 = csr[p + 2], s3 = csr[p + 3];
                float a0 = b2f(xW16[((s0 << 3) + r) * HID_CH + c]);
                float a1 = b2f(xW16[((s1 << 3) + r) * HID_CH + c]);
                float a2 = b2f(xW16[((s2 << 3) + r) * HID_CH + c]);
                float a3 = b2f(xW16[((s3 << 3) + r) * HID_CH + c]);
                seg += (a0 + a1) + (a2 + a3);
            }
            for (; p < end; ++p) {
                int s0 = csr[p];
                seg += b2f(xW16[((s0 << 3) + r) * HID_CH + c]);
            }
            acc += seg * (1.0f / (float)len);
            prev = end;
        }
    }

    const float4* xs = (const float4*)(x + ((long)node << 4));
    float4 v0 = xs[0], v1 = xs[1], v2 = xs[2], v3 = xs[3];
    const float* wr = root1 + c;
    acc += b1[c];
    acc += v0.x * wr[0]   + v0.y * wr[32]  + v0.z * wr[64]  + v0.w * wr[96];
    acc += v1.x * wr[128] + v1.y * wr[160] + v1.z * wr[192] + v1.w * wr[224];
    acc += v2.x * wr[256] + v2.y * wr[288] + v2.z * wr[320] + v2.w * wr[352];
    acc += v3.x * wr[384] + v3.y * wr[416] + v3.z * wr[448] + v3.w * wr[480];
    h[(node << 5) + c] = fmaxf(acc, 0.0f);
}

// ---------------------------------------------------------------------------
// l1 fallback (no room for xW16): direct per-edge dot
// ---------------------------------------------------------------------------
__global__ __launch_bounds__(256) void l1_fb_kernel(const float* __restrict__ x,
                                                    const int* __restrict__ csr,
                                                    const int* __restrict__ ends,
                                                    const float* __restrict__ W1,
                                                    const float* __restrict__ root1,
                                                    const float* __restrict__ b1,
                                                    float* __restrict__ h, int N) {
    int gid  = blockIdx.x * 256 + threadIdx.x;
    int node = gid >> 5;
    int c    = gid & 31;
    if (node >= N) return;

    int4 e0 = ((const int4*)ends)[node * 2];
    int4 e1 = ((const int4*)ends)[node * 2 + 1];
    int end_r[N_REL] = {e0.x, e0.y, e0.z, e0.w, e1.x, e1.y, e1.z, e1.w};

    int prev = (node > 0) ? __ldg(&ends[node * N_REL - 1]) : 0;
    float acc = 0.0f;

#pragma unroll
    for (int r = 0; r < N_REL; ++r) {
        int end = end_r[r];
        int len = end - prev;
        if (len > 0) {
            const float* wp = W1 + (r * IN_CH) * HID_CH + c;
            float w[IN_CH];
#pragma unroll
            for (int f = 0; f < IN_CH; ++f) w[f] = wp[f * HID_CH];
            float seg = 0.0f;
            for (int p = prev; p < end; ++p) {
                int s = csr[p];
                const float4* xs = (const float4*)(x + ((long)s << 4));
                float4 v0 = xs[0], v1 = xs[1], v2 = xs[2], v3 = xs[3];
                float a;
                a  = v0.x * w[0]  + v0.y * w[1]  + v0.z * w[2]  + v0.w * w[3];
                a += v1.x * w[4]  + v1.y * w[5]  + v1.z * w[6]  + v1.w * w[7];
                a += v2.x * w[8]  + v2.y * w[9]  + v2.z * w[10] + v2.w * w[11];
                a += v3.x * w[12] + v3.y * w[13] + v3.z * w[14] + v3.w * w[15];
                seg += a;
            }
            acc += seg * (1.0f / (float)len);
            prev = end;
        }
    }

    const float4* xs = (const float4*)(x + ((long)node << 4));
    float4 v0 = xs[0], v1 = xs[1], v2 = xs[2], v3 = xs[3];
    const float* wr = root1 + c;
    acc += b1[c];
    acc += v0.x * wr[0]   + v0.y * wr[32]  + v0.z * wr[64]  + v0.w * wr[96];
    acc += v1.x * wr[128] + v1.y * wr[160] + v1.z * wr[192] + v1.w * wr[224];
    acc += v2.x * wr[256] + v2.y * wr[288] + v2.z * wr[320] + v2.w * wr[352];
    acc += v3.x * wr[384] + v3.y * wr[416] + v3.z * wr[448] + v3.w * wr[480];
    h[(node << 5) + c] = fmaxf(acc, 0.0f);
}

// ---------------------------------------------------------------------------
// hw: hW16[n][r] = packed bf16x2( h[n] @ W2[r] )  (3.2MB, L2-resident gather
// table for l2_finish); hroot[n] = h[n]@root2 + b2 (float2)
// ---------------------------------------------------------------------------
__global__ __launch_bounds__(256) void hw_kernel(const float* __restrict__ h,
                                                 const float* __restrict__ W2,
                                                 const float* __restrict__ root2,
                                                 const float* __restrict__ b2,
                                                 unsigned int* __restrict__ hW16,
                                                 float* __restrict__ hroot, int N) {
    int gid = blockIdx.x * 256 + threadIdx.x;
    if (gid >= N * 9) return;
    int n = gid / 9;
    int j = gid - n * 9;

    const float* hn = h + ((long)n << 5);
    const float* wp = (j < 8) ? (W2 + j * (HID_CH * OUT_CH)) : root2;

    float o0 = 0.0f, o1 = 0.0f;
#pragma unroll
    for (int f = 0; f < HID_CH; ++f) {
        float hf = hn[f];
        o0 += hf * wp[f * 2 + 0];
        o1 += hf * wp[f * 2 + 1];
    }
    if (j < 8) {
        hW16[(n << 3) + j] = ((unsigned)f2b(o1) << 16) | f2b(o0);
    } else {
        *(float2*)(hroot + ((long)n << 1)) = make_float2(o0 + b2[0], o1 + b2[1]);
    }
}

// ---------------------------------------------------------------------------
// l2 finish: 8 lanes per node, lane = relation; 4B gathers from L2-resident
// hW16 table, 4-deep load pipeline; shuffle-reduce + log_softmax.
// ---------------------------------------------------------------------------
__global__ __launch_bounds__(256) void l2_finish_kernel(const int* __restrict__ csr,
                                                        const int* __restrict__ ends,
                                                        const unsigned int* __restrict__ hW16,
                                                        const float* __restrict__ hroot,
                                                        float* __restrict__ out, int N) {
    int gid  = blockIdx.x * 256 + threadIdx.x;
    int node = gid >> 3;
    int r    = gid & 7;
    if (node >= N) return;

    int idx  = node * N_REL + r;
    int prev = (idx > 0) ? ends[idx - 1] : 0;
    int end  = ends[idx];

    float o0 = 0.0f, o1 = 0.0f;
    if (end > prev) {
        float s0 = 0.0f, s1 = 0.0f;
        int p = prev;
        for (; p + 3 < end; p += 4) {
            int a = csr[p], b = csr[p + 1], c = csr[p + 2], d = csr[p + 3];
            unsigned va = hW16[(a << 3) + r];
            unsigned vb = hW16[(b << 3) + r];
            unsigned vc = hW16[(c << 3) + r];
            unsigned vd = hW16[(d << 3) + r];
            s0 += b2f((unsigned short)va) + b2f((unsigned short)vb)
                + b2f((unsigned short)vc) + b2f((unsigned short)vd);
            s1 += b2f((unsigned short)(va >> 16)) + b2f((unsigned short)(vb >> 16))
                + b2f((unsigned short)(vc >> 16)) + b2f((unsigned short)(vd >> 16));
        }
        for (; p < end; ++p) {
            unsigned va = hW16[(csr[p] << 3) + r];
            s0 += b2f((unsigned short)va);
            s1 += b2f((unsigned short)(va >> 16));
        }
        float inv = 1.0f / (float)(end - prev);
        o0 = s0 * inv; o1 = s1 * inv;
    }

#pragma unroll
    for (int m = 1; m < 8; m <<= 1) {
        o0 += __shfl_xor(o0, m, 64);
        o1 += __shfl_xor(o1, m, 64);
    }

    if (r == 0) {
        float2 rt = *(const float2*)(hroot + ((long)node << 1));
        o0 += rt.x; o1 += rt.y;
        float mx = fmaxf(o0, o1);
        float l  = mx + logf(__expf(o0 - mx) + __expf(o1 - mx));
        *(float2*)(out + ((long)node << 1)) = make_float2(o0 - l, o1 - l);
    }
}

// ---------------------------------------------------------------------------
extern "C" void kernel_launch(void* const* d_in, const int* in_sizes, int n_in,
                              void* d_out, int out_size, void* d_ws, size_t ws_size,
                              hipStream_t stream) {
    const float* x     = (const float*)d_in[0];
    const int*   eidx  = (const int*)d_in[1];
    const int*   etype = (const int*)d_in[2];
    const float* W1    = (const float*)d_in[3];
    const float* root1 = (const float*)d_in[4];
    const float* b1    = (const float*)d_in[5];
    const float* W2    = (const float*)d_in[6];
    const float* root2 = (const float*)d_in[7];
    const float* b2    = (const float*)d_in[8];
    float* out = (float*)d_out;

    const int N = in_sizes[0] / IN_CH;
    const int E = in_sizes[2];
    const int nbins   = (N + BIN_NODES - 1) >> BIN_BITS;
    const int chunksz = (E + NCHUNK - 1) / NCHUNK;
    const int M2      = nbins * NCHUNK;
    const int* src = eidx;
    const int* dst = eidx + E;

    char* wp = (char*)d_ws;
    auto take = [&](size_t bytes) {
        char* p = wp;
        wp += (bytes + 63) & ~(size_t)63;
        return p;
    };
    int*   H      = (int*)take((size_t)M2 * sizeof(int));
    int*   blksum = (int*)take(4096 * sizeof(int));
    int*   ends   = (int*)take((size_t)nbins * KPB * sizeof(int));
    int*   csr    = (int*)take((size_t)E * sizeof(int));
    float* h      = (float*)take((size_t)N * HID_CH * sizeof(float));
    unsigned int* hW16 = (unsigned int*)take((size_t)N * N_REL * sizeof(unsigned int));
    float* hroot  = (float*)take((size_t)N * 2 * sizeof(float));
    unsigned short* xW16 = (unsigned short*)take((size_t)N * N_REL * HID_CH * sizeof(unsigned short));
    bool use_xw = ((size_t)(wp - (char*)d_ws) <= ws_size);
    int* be = (int*)h;   // alias: be dead before h's first write (l1 after bin_build)

    const int B = 256;
    const int nb = (M2 + 1023) / 1024;

    part_hist_kernel<<<NCHUNK, B, 0, stream>>>(dst, H, E, nbins, chunksz);
    scan_a_kernel<<<nb, 1024, 0, stream>>>(H, blksum, M2);
    scan_b_kernel<<<1, 64, 0, stream>>>(blksum, nb);
    scan_c_kernel<<<nb, 1024, 0, stream>>>(H, blksum, M2);
    part_scatter_kernel<<<NCHUNK, B, 0, stream>>>(src, dst, etype, H, be, E, nbins, chunksz);
    bin_build_kernel<<<nbins, B, 0, stream>>>(be, H, ends, csr, E, nbins);

    if (use_xw) {
        xw_kernel<<<(N + XW_TILE - 1) / XW_TILE, B, 0, stream>>>(x, W1, xW16, N);
        l1_gather_kernel<<<(N * 32 + B - 1) / B, B, 0, stream>>>(x, csr, ends, xW16, root1, b1, h, N);
    } else {
        l1_fb_kernel<<<(N * 32 + B - 1) / B, B, 0, stream>>>(x, csr, ends, W1, root1, b1, h, N);
    }

    hw_kernel<<<(N * 9 + B - 1) / B, B, 0, stream>>>(h, W2, root2, b2, hW16, hroot, N);
    l2_finish_kernel<<<(N * 8 + B - 1) / B, B, 0, stream>>>(csr, ends, hW16, hroot, out, N);
}

// Round 10
// 192.954 us; speedup vs baseline: 1.7711x; 1.2082x over previous
//
#include <hip/hip_runtime.h>
#include <math.h>

#define N_REL  8
#define IN_CH  16
#define HID_CH 32
#define OUT_CH 2

#define BIN_BITS  9
#define BIN_NODES 512                    // nodes per coarse bin
#define KPB       (BIN_NODES * N_REL)    // 4096 (node,rel) keys per bin
#define NCHUNK    192                    // partition chunks (blocks)

// float -> bf16 round-to-nearest-even
static __device__ __forceinline__ unsigned short f2b(float f) {
    unsigned int u = __float_as_uint(f);
    u = (u + 0x7FFFu + ((u >> 16) & 1u)) >> 16;
    return (unsigned short)u;
}
static __device__ __forceinline__ float b2f(unsigned short s) {
    return __uint_as_float(((unsigned int)s) << 16);
}

// ---------------------------------------------------------------------------
// B1a: per-chunk histogram over coarse bins (LDS), H[bin][chunk] (bin-major)
// ---------------------------------------------------------------------------
__global__ __launch_bounds__(256) void part_hist_kernel(const int* __restrict__ dst,
                                                        int* __restrict__ H,
                                                        int E, int nbins, int chunksz) {
    __shared__ int hist[256];
    int chunk = blockIdx.x;
    int e0 = chunk * chunksz;
    int e1 = e0 + chunksz; if (e1 > E) e1 = E;

    for (int i = threadIdx.x; i < nbins; i += 256) hist[i] = 0;
    __syncthreads();
    for (int e = e0 + threadIdx.x; e < e1; e += 256)
        atomicAdd(&hist[dst[e] >> BIN_BITS], 1);
    __syncthreads();
    for (int i = threadIdx.x; i < nbins; i += 256)
        H[i * NCHUNK + chunk] = hist[i];
}

// ---------------------------------------------------------------------------
// scan_a/b/c: exclusive scan of H[0..M2) in place
// ---------------------------------------------------------------------------
__global__ __launch_bounds__(1024) void scan_a_kernel(int* __restrict__ ptr,
                                                      int* __restrict__ blksum, int M) {
    int i = blockIdx.x * 1024 + threadIdx.x;
    int val = (i < M) ? ptr[i] : 0;
    int lane = threadIdx.x & 63;
    int wid  = threadIdx.x >> 6;

    int v = val;
#pragma unroll
    for (int off = 1; off < 64; off <<= 1) {
        int u = __shfl_up(v, off, 64);
        if (lane >= off) v += u;
    }

    __shared__ int wsum[16];
    if (lane == 63) wsum[wid] = v;
    __syncthreads();

    if (wid == 0) {
        int worig = (lane < 16) ? wsum[lane] : 0;
        int wv = worig;
#pragma unroll
        for (int off = 1; off < 16; off <<= 1) {
            int u = __shfl_up(wv, off, 64);
            if (lane >= off) wv += u;
        }
        if (lane < 16) wsum[lane] = wv - worig;
        if (lane == 15) blksum[blockIdx.x] = wv;
    }
    __syncthreads();

    if (i < M) ptr[i] = (v - val) + wsum[wid];
}

__global__ void scan_b_kernel(int* __restrict__ blksum, int nb) {
    int lane = threadIdx.x & 63;
    int run = 0;
    for (int base = 0; base < nb; base += 64) {
        int i = base + lane;
        int val = (i < nb) ? blksum[i] : 0;
        int v = val;
#pragma unroll
        for (int off = 1; off < 64; off <<= 1) {
            int u = __shfl_up(v, off, 64);
            if (lane >= off) v += u;
        }
        if (i < nb) blksum[i] = run + (v - val);
        run += __shfl(v, 63, 64);
    }
}

__global__ __launch_bounds__(1024) void scan_c_kernel(int* __restrict__ ptr,
                                                      const int* __restrict__ blksum, int M) {
    int i = blockIdx.x * 1024 + threadIdx.x;
    if (i < M) ptr[i] += blksum[blockIdx.x];
}

// ---------------------------------------------------------------------------
// B1b: partition — chunk-block writes packed records to per-(bin,chunk) runs.
// pack: (localdst<<20) | (rel<<17) | src   (src < 2^17, localdst < 512)
// ---------------------------------------------------------------------------
__global__ __launch_bounds__(256) void part_scatter_kernel(const int* __restrict__ src,
                                                           const int* __restrict__ dst,
                                                           const int* __restrict__ rel,
                                                           const int* __restrict__ Hs,
                                                           int* __restrict__ be,
                                                           int E, int nbins, int chunksz) {
    __shared__ int base[256];
    __shared__ int fil[256];
    int chunk = blockIdx.x;
    int e0 = chunk * chunksz;
    int e1 = e0 + chunksz; if (e1 > E) e1 = E;

    for (int i = threadIdx.x; i < nbins; i += 256) {
        base[i] = Hs[i * NCHUNK + chunk];
        fil[i]  = 0;
    }
    __syncthreads();

    for (int e = e0 + threadIdx.x; e < e1; e += 256) {
        int d = dst[e];
        int b = d >> BIN_BITS;
        int slot = base[b] + atomicAdd(&fil[b], 1);
        be[slot] = ((d & (BIN_NODES - 1)) << 20) | (rel[e] << 17) | src[e];
    }
}

// ---------------------------------------------------------------------------
// B2: one block per bin — LDS counting sort over 4096 keys -> ends[], csr[],
// einv[]. csr entry = (src<<3)|rel; einv = 1/segment_len (per edge).
// ---------------------------------------------------------------------------
__global__ __launch_bounds__(256) void bin_build_kernel(const int* __restrict__ be,
                                                        const int* __restrict__ Hs,
                                                        int* __restrict__ ends,
                                                        int* __restrict__ csr,
                                                        float* __restrict__ einv,
                                                        int E, int nbins) {
    int b  = blockIdx.x;
    int s0 = Hs[b * NCHUNK];
    int s1 = (b + 1 < nbins) ? Hs[(b + 1) * NCHUNK] : E;
    int t  = threadIdx.x;

    __shared__ int cnt[KPB];
    __shared__ int off[KPB];
    __shared__ int fil[KPB];
    __shared__ int ws[4];

    for (int i = t; i < KPB; i += 256) { cnt[i] = 0; fil[i] = 0; }
    __syncthreads();

    for (int p = s0 + t; p < s1; p += 256)
        atomicAdd(&cnt[be[p] >> 17], 1);          // key = (localdst<<3)|rel
    __syncthreads();

    int kbase = t * 16;
    int loc[16];
    int sum = 0;
#pragma unroll
    for (int i = 0; i < 16; ++i) { loc[i] = sum; sum += cnt[kbase + i]; }

    int lane = t & 63, wid = t >> 6;
    int v = sum;
#pragma unroll
    for (int o = 1; o < 64; o <<= 1) {
        int u = __shfl_up(v, o, 64);
        if (lane >= o) v += u;
    }
    if (lane == 63) ws[wid] = v;
    __syncthreads();
    int woff = 0;
    for (int i = 0; i < wid; ++i) woff += ws[i];
    int excl = woff + (v - sum);
#pragma unroll
    for (int i = 0; i < 16; ++i) off[kbase + i] = excl + loc[i];
    __syncthreads();

    for (int i = t; i < KPB; i += 256)
        ends[b * KPB + i] = s0 + off[i] + cnt[i];

    for (int p = s0 + t; p < s1; p += 256) {
        int pk = be[p];
        int k  = pk >> 17;
        int slot = s0 + off[k] + atomicAdd(&fil[k], 1);
        csr[slot]  = ((pk & 0x1FFFF) << 3) | (k & 7);
        einv[slot] = 1.0f / (float)cnt[k];
    }
}

// ---------------------------------------------------------------------------
// xw: xW16[n][r][c] = bf16( x[n] @ W1[r][:,c] )
// ---------------------------------------------------------------------------
#define XW_TILE 64
__global__ __launch_bounds__(256) void xw_kernel(const float* __restrict__ x,
                                                 const float* __restrict__ W1,
                                                 unsigned short* __restrict__ xW16, int N) {
    __shared__ float sx[XW_TILE * IN_CH];   // 4 KB
    int t = threadIdx.x;
    int node0 = blockIdx.x * XW_TILE;

    {
        int i4 = node0 * 4 + t;
        float4 v = make_float4(0.f, 0.f, 0.f, 0.f);
        if (i4 < N * 4) v = ((const float4*)x)[i4];
        ((float4*)sx)[t] = v;
    }
    __syncthreads();

    int r = t >> 5, c = t & 31;
    float w[IN_CH];
#pragma unroll
    for (int f = 0; f < IN_CH; ++f)
        w[f] = W1[(r * IN_CH + f) * HID_CH + c];

    int lim = N - node0; if (lim > XW_TILE) lim = XW_TILE;
    for (int ni = 0; ni < lim; ++ni) {
        const float4* xs = (const float4*)(sx + ni * IN_CH);
        float4 v0 = xs[0], v1 = xs[1], v2 = xs[2], v3 = xs[3];
        float a;
        a  = v0.x * w[0]  + v0.y * w[1]  + v0.z * w[2]  + v0.w * w[3];
        a += v1.x * w[4]  + v1.y * w[5]  + v1.z * w[6]  + v1.w * w[7];
        a += v2.x * w[8]  + v2.y * w[9]  + v2.z * w[10] + v2.w * w[11];
        a += v3.x * w[12] + v3.y * w[13] + v3.z * w[14] + v3.w * w[15];
        xW16[(node0 + ni) * (N_REL * HID_CH) + t] = f2b(a);
    }
}

// ---------------------------------------------------------------------------
// l1 gather: half-wave per node, lane = channel c. FLAT edge loop: the node's
// ~16 edges (all rels, contiguous in csr) processed 4-deep with per-edge
// norm from einv — max memory-level parallelism, no per-segment serialization.
// ---------------------------------------------------------------------------
__global__ __launch_bounds__(256) void l1_gather_kernel(const float* __restrict__ x,
                                                        const int* __restrict__ csr,
                                                        const float* __restrict__ einv,
                                                        const int* __restrict__ ends,
                                                        const unsigned short* __restrict__ xW16,
                                                        const float* __restrict__ root1,
                                                        const float* __restrict__ b1,
                                                        float* __restrict__ h, int N) {
    int gid  = blockIdx.x * 256 + threadIdx.x;
    int node = gid >> 5;
    int c    = gid & 31;
    if (node >= N) return;

    int p0 = (node > 0) ? __ldg(&ends[node * N_REL - 1]) : 0;
    int p1 = __ldg(&ends[node * N_REL + N_REL - 1]);

    float acc = 0.0f;
    int p = p0;
    for (; p + 3 < p1; p += 4) {            // 4 fully independent edge chains
        int v0 = csr[p], v1 = csr[p + 1], v2 = csr[p + 2], v3 = csr[p + 3];
        float i0 = einv[p], i1 = einv[p + 1], i2 = einv[p + 2], i3 = einv[p + 3];
        float a0 = b2f(xW16[(v0 << 5) + c]);
        float a1 = b2f(xW16[(v1 << 5) + c]);
        float a2 = b2f(xW16[(v2 << 5) + c]);
        float a3 = b2f(xW16[(v3 << 5) + c]);
        acc = fmaf(a0, i0, acc);
        acc = fmaf(a1, i1, acc);
        acc = fmaf(a2, i2, acc);
        acc = fmaf(a3, i3, acc);
    }
    if (p + 1 < p1) {                        // 2-deep tail
        int v0 = csr[p], v1 = csr[p + 1];
        float i0 = einv[p], i1 = einv[p + 1];
        acc = fmaf(b2f(xW16[(v0 << 5) + c]), i0, acc);
        acc = fmaf(b2f(xW16[(v1 << 5) + c]), i1, acc);
        p += 2;
    }
    if (p < p1)
        acc = fmaf(b2f(xW16[(csr[p] << 5) + c]), einv[p], acc);

    const float4* xs = (const float4*)(x + ((long)node << 4));
    float4 v0 = xs[0], v1 = xs[1], v2 = xs[2], v3 = xs[3];
    const float* wr = root1 + c;
    acc += b1[c];
    acc += v0.x * wr[0]   + v0.y * wr[32]  + v0.z * wr[64]  + v0.w * wr[96];
    acc += v1.x * wr[128] + v1.y * wr[160] + v1.z * wr[192] + v1.w * wr[224];
    acc += v2.x * wr[256] + v2.y * wr[288] + v2.z * wr[320] + v2.w * wr[352];
    acc += v3.x * wr[384] + v3.y * wr[416] + v3.z * wr[448] + v3.w * wr[480];
    h[(node << 5) + c] = fmaxf(acc, 0.0f);
}

// ---------------------------------------------------------------------------
// l1 fallback (no room for xW16): flat loop, direct per-edge dot (csr packed)
// ---------------------------------------------------------------------------
__global__ __launch_bounds__(256) void l1_fb_kernel(const float* __restrict__ x,
                                                    const int* __restrict__ csr,
                                                    const float* __restrict__ einv,
                                                    const int* __restrict__ ends,
                                                    const float* __restrict__ W1,
                                                    const float* __restrict__ root1,
                                                    const float* __restrict__ b1,
                                                    float* __restrict__ h, int N) {
    __shared__ float sW[N_REL * IN_CH * HID_CH];   // 16 KB
    for (int i = threadIdx.x; i < N_REL * IN_CH * HID_CH; i += 256)
        sW[i] = W1[i];
    __syncthreads();

    int gid  = blockIdx.x * 256 + threadIdx.x;
    int node = gid >> 5;
    int c    = gid & 31;
    if (node >= N) return;

    int p0 = (node > 0) ? __ldg(&ends[node * N_REL - 1]) : 0;
    int p1 = __ldg(&ends[node * N_REL + N_REL - 1]);

    float acc = 0.0f;
    for (int p = p0; p < p1; ++p) {
        int v = csr[p];
        int s = v >> 3, r = v & 7;
        const float4* xs = (const float4*)(x + ((long)s << 4));
        float4 v0 = xs[0], v1 = xs[1], v2 = xs[2], v3 = xs[3];
        const float* w = sW + ((r * IN_CH) * HID_CH) + c;
        float a;
        a  = v0.x * w[0]   + v0.y * w[32]  + v0.z * w[64]  + v0.w * w[96];
        a += v1.x * w[128] + v1.y * w[160] + v1.z * w[192] + v1.w * w[224];
        a += v2.x * w[256] + v2.y * w[288] + v2.z * w[320] + v2.w * w[352];
        a += v3.x * w[384] + v3.y * w[416] + v3.z * w[448] + v3.w * w[480];
        acc = fmaf(a, einv[p], acc);
    }

    const float4* xs = (const float4*)(x + ((long)node << 4));
    float4 v0 = xs[0], v1 = xs[1], v2 = xs[2], v3 = xs[3];
    const float* wr = root1 + c;
    acc += b1[c];
    acc += v0.x * wr[0]   + v0.y * wr[32]  + v0.z * wr[64]  + v0.w * wr[96];
    acc += v1.x * wr[128] + v1.y * wr[160] + v1.z * wr[192] + v1.w * wr[224];
    acc += v2.x * wr[256] + v2.y * wr[288] + v2.z * wr[320] + v2.w * wr[352];
    acc += v3.x * wr[384] + v3.y * wr[416] + v3.z * wr[448] + v3.w * wr[480];
    h[(node << 5) + c] = fmaxf(acc, 0.0f);
}

// ---------------------------------------------------------------------------
// hw: hW16[n][r] = packed bf16x2( h[n] @ W2[r] );  hroot[n] = h[n]@root2 + b2
// ---------------------------------------------------------------------------
__global__ __launch_bounds__(256) void hw_kernel(const float* __restrict__ h,
                                                 const float* __restrict__ W2,
                                                 const float* __restrict__ root2,
                                                 const float* __restrict__ b2,
                                                 unsigned int* __restrict__ hW16,
                                                 float* __restrict__ hroot, int N) {
    int gid = blockIdx.x * 256 + threadIdx.x;
    if (gid >= N * 9) return;
    int n = gid / 9;
    int j = gid - n * 9;

    const float* hn = h + ((long)n << 5);
    const float* wp = (j < 8) ? (W2 + j * (HID_CH * OUT_CH)) : root2;

    float o0 = 0.0f, o1 = 0.0f;
#pragma unroll
    for (int f = 0; f < HID_CH; ++f) {
        float hf = hn[f];
        o0 += hf * wp[f * 2 + 0];
        o1 += hf * wp[f * 2 + 1];
    }
    if (j < 8) {
        hW16[(n << 3) + j] = ((unsigned)f2b(o1) << 16) | f2b(o0);
    } else {
        *(float2*)(hroot + ((long)n << 1)) = make_float2(o0 + b2[0], o1 + b2[1]);
    }
}

// ---------------------------------------------------------------------------
// l2 finish: 8 lanes per node, lane = relation; 4B gathers from L2-resident
// hW16 table, 2-deep (matches mean segment len); shuffle-reduce + log_softmax.
// ---------------------------------------------------------------------------
__global__ __launch_bounds__(256) void l2_finish_kernel(const int* __restrict__ csr,
                                                        const int* __restrict__ ends,
                                                        const unsigned int* __restrict__ hW16,
                                                        const float* __restrict__ hroot,
                                                        float* __restrict__ out, int N) {
    int gid  = blockIdx.x * 256 + threadIdx.x;
    int node = gid >> 3;
    int r    = gid & 7;
    if (node >= N) return;

    int idx  = node * N_REL + r;
    int prev = (idx > 0) ? ends[idx - 1] : 0;
    int end  = ends[idx];

    float o0 = 0.0f, o1 = 0.0f;
    if (end > prev) {
        float s0 = 0.0f, s1 = 0.0f;
        int p = prev;
        for (; p + 1 < end; p += 2) {
            int a = csr[p] >> 3, b = csr[p + 1] >> 3;
            unsigned va = hW16[(a << 3) + r];
            unsigned vb = hW16[(b << 3) + r];
            s0 += b2f((unsigned short)va) + b2f((unsigned short)vb);
            s1 += b2f((unsigned short)(va >> 16)) + b2f((unsigned short)(vb >> 16));
        }
        if (p < end) {
            unsigned va = hW16[((csr[p] >> 3) << 3) + r];
            s0 += b2f((unsigned short)va);
            s1 += b2f((unsigned short)(va >> 16));
        }
        float inv = 1.0f / (float)(end - prev);
        o0 = s0 * inv; o1 = s1 * inv;
    }

#pragma unroll
    for (int m = 1; m < 8; m <<= 1) {
        o0 += __shfl_xor(o0, m, 64);
        o1 += __shfl_xor(o1, m, 64);
    }

    if (r == 0) {
        float2 rt = *(const float2*)(hroot + ((long)node << 1));
        o0 += rt.x; o1 += rt.y;
        float mx = fmaxf(o0, o1);
        float l  = mx + logf(__expf(o0 - mx) + __expf(o1 - mx));
        *(float2*)(out + ((long)node << 1)) = make_float2(o0 - l, o1 - l);
    }
}

// ---------------------------------------------------------------------------
extern "C" void kernel_launch(void* const* d_in, const int* in_sizes, int n_in,
                              void* d_out, int out_size, void* d_ws, size_t ws_size,
                              hipStream_t stream) {
    const float* x     = (const float*)d_in[0];
    const int*   eidx  = (const int*)d_in[1];
    const int*   etype = (const int*)d_in[2];
    const float* W1    = (const float*)d_in[3];
    const float* root1 = (const float*)d_in[4];
    const float* b1    = (const float*)d_in[5];
    const float* W2    = (const float*)d_in[6];
    const float* root2 = (const float*)d_in[7];
    const float* b2    = (const float*)d_in[8];
    float* out = (float*)d_out;

    const int N = in_sizes[0] / IN_CH;
    const int E = in_sizes[2];
    const int nbins   = (N + BIN_NODES - 1) >> BIN_BITS;
    const int chunksz = (E + NCHUNK - 1) / NCHUNK;
    const int M2      = nbins * NCHUNK;
    const int* src = eidx;
    const int* dst = eidx + E;

    char* wp = (char*)d_ws;
    auto take = [&](size_t bytes) {
        char* p = wp;
        wp += (bytes + 63) & ~(size_t)63;
        return p;
    };
    int*   H      = (int*)take((size_t)M2 * sizeof(int));
    int*   blksum = (int*)take(4096 * sizeof(int));
    int*   ends   = (int*)take((size_t)nbins * KPB * sizeof(int));
    int*   csr    = (int*)take((size_t)E * sizeof(int));
    float* einv   = (float*)take((size_t)E * sizeof(float));
    float* h      = (float*)take((size_t)N * HID_CH * sizeof(float));
    unsigned int* hW16 = (unsigned int*)take((size_t)N * N_REL * sizeof(unsigned int));
    float* hroot  = (float*)take((size_t)N * 2 * sizeof(float));
    unsigned short* xW16 = (unsigned short*)take((size_t)N * N_REL * HID_CH * sizeof(unsigned short));
    bool use_xw = ((size_t)(wp - (char*)d_ws) <= ws_size);
    int* be = (int*)h;   // alias: be dead before h's first write (l1 after bin_build)

    const int B = 256;
    const int nb = (M2 + 1023) / 1024;

    part_hist_kernel<<<NCHUNK, B, 0, stream>>>(dst, H, E, nbins, chunksz);
    scan_a_kernel<<<nb, 1024, 0, stream>>>(H, blksum, M2);
    scan_b_kernel<<<1, 64, 0, stream>>>(blksum, nb);
    scan_c_kernel<<<nb, 1024, 0, stream>>>(H, blksum, M2);
    part_scatter_kernel<<<NCHUNK, B, 0, stream>>>(src, dst, etype, H, be, E, nbins, chunksz);
    bin_build_kernel<<<nbins, B, 0, stream>>>(be, H, ends, csr, einv, E, nbins);

    if (use_xw) {
        xw_kernel<<<(N + XW_TILE - 1) / XW_TILE, B, 0, stream>>>(x, W1, xW16, N);
        l1_gather_kernel<<<(N * 32 + B - 1) / B, B, 0, stream>>>(x, csr, einv, ends, xW16, root1, b1, h, N);
    } else {
        l1_fb_kernel<<<(N * 32 + B - 1) / B, B, 0, stream>>>(x, csr, einv, ends, W1, root1, b1, h, N);
    }

    hw_kernel<<<(N * 9 + B - 1) / B, B, 0, stream>>>(h, W2, root2, b2, hW16, hroot, N);
    l2_finish_kernel<<<(N * 8 + B - 1) / B, B, 0, stream>>>(csr, ends, hW16, hroot, out, N);
}

// Round 11
// 166.967 us; speedup vs baseline: 2.0468x; 1.1556x over previous
//
#include <hip/hip_runtime.h>
#include <math.h>

#define N_REL  8
#define IN_CH  16
#define HID_CH 32
#define OUT_CH 2

#define BIN_BITS  9
#define BIN_NODES 512                    // nodes per coarse bin
#define KPB       (BIN_NODES * N_REL)    // 4096 (node,rel) keys per bin
#define NCHUNK    192                    // partition chunks (blocks)

// float -> bf16 round-to-nearest-even
static __device__ __forceinline__ unsigned short f2b(float f) {
    unsigned int u = __float_as_uint(f);
    u = (u + 0x7FFFu + ((u >> 16) & 1u)) >> 16;
    return (unsigned short)u;
}
static __device__ __forceinline__ float b2f(unsigned short s) {
    return __uint_as_float(((unsigned int)s) << 16);
}

// ---------------------------------------------------------------------------
// B1a: per-chunk histogram over coarse bins (LDS), H[bin][chunk] (bin-major)
// ---------------------------------------------------------------------------
__global__ __launch_bounds__(256) void part_hist_kernel(const int* __restrict__ dst,
                                                        int* __restrict__ H,
                                                        int E, int nbins, int chunksz) {
    __shared__ int hist[256];
    int chunk = blockIdx.x;
    int e0 = chunk * chunksz;
    int e1 = e0 + chunksz; if (e1 > E) e1 = E;

    for (int i = threadIdx.x; i < nbins; i += 256) hist[i] = 0;
    __syncthreads();
    for (int e = e0 + threadIdx.x; e < e1; e += 256)
        atomicAdd(&hist[dst[e] >> BIN_BITS], 1);
    __syncthreads();
    for (int i = threadIdx.x; i < nbins; i += 256)
        H[i * NCHUNK + chunk] = hist[i];
}

// ---------------------------------------------------------------------------
// scan_a/b/c: exclusive scan of H[0..M2) in place
// ---------------------------------------------------------------------------
__global__ __launch_bounds__(1024) void scan_a_kernel(int* __restrict__ ptr,
                                                      int* __restrict__ blksum, int M) {
    int i = blockIdx.x * 1024 + threadIdx.x;
    int val = (i < M) ? ptr[i] : 0;
    int lane = threadIdx.x & 63;
    int wid  = threadIdx.x >> 6;

    int v = val;
#pragma unroll
    for (int off = 1; off < 64; off <<= 1) {
        int u = __shfl_up(v, off, 64);
        if (lane >= off) v += u;
    }

    __shared__ int wsum[16];
    if (lane == 63) wsum[wid] = v;
    __syncthreads();

    if (wid == 0) {
        int worig = (lane < 16) ? wsum[lane] : 0;
        int wv = worig;
#pragma unroll
        for (int off = 1; off < 16; off <<= 1) {
            int u = __shfl_up(wv, off, 64);
            if (lane >= off) wv += u;
        }
        if (lane < 16) wsum[lane] = wv - worig;
        if (lane == 15) blksum[blockIdx.x] = wv;
    }
    __syncthreads();

    if (i < M) ptr[i] = (v - val) + wsum[wid];
}

__global__ void scan_b_kernel(int* __restrict__ blksum, int nb) {
    int lane = threadIdx.x & 63;
    int run = 0;
    for (int base = 0; base < nb; base += 64) {
        int i = base + lane;
        int val = (i < nb) ? blksum[i] : 0;
        int v = val;
#pragma unroll
        for (int off = 1; off < 64; off <<= 1) {
            int u = __shfl_up(v, off, 64);
            if (lane >= off) v += u;
        }
        if (i < nb) blksum[i] = run + (v - val);
        run += __shfl(v, 63, 64);
    }
}

__global__ __launch_bounds__(1024) void scan_c_kernel(int* __restrict__ ptr,
                                                      const int* __restrict__ blksum, int M) {
    int i = blockIdx.x * 1024 + threadIdx.x;
    if (i < M) ptr[i] += blksum[blockIdx.x];
}

// ---------------------------------------------------------------------------
// B1b: partition — chunk-block writes packed records to per-(bin,chunk) runs.
// pack: (localdst<<20) | (rel<<17) | src   (src < 2^17, localdst < 512)
// ---------------------------------------------------------------------------
__global__ __launch_bounds__(256) void part_scatter_kernel(const int* __restrict__ src,
                                                           const int* __restrict__ dst,
                                                           const int* __restrict__ rel,
                                                           const int* __restrict__ Hs,
                                                           int* __restrict__ be,
                                                           int E, int nbins, int chunksz) {
    __shared__ int base[256];
    __shared__ int fil[256];
    int chunk = blockIdx.x;
    int e0 = chunk * chunksz;
    int e1 = e0 + chunksz; if (e1 > E) e1 = E;

    for (int i = threadIdx.x; i < nbins; i += 256) {
        base[i] = Hs[i * NCHUNK + chunk];
        fil[i]  = 0;
    }
    __syncthreads();

    for (int e = e0 + threadIdx.x; e < e1; e += 256) {
        int d = dst[e];
        int b = d >> BIN_BITS;
        int slot = base[b] + atomicAdd(&fil[b], 1);
        be[slot] = ((d & (BIN_NODES - 1)) << 20) | (rel[e] << 17) | src[e];
    }
}

// ---------------------------------------------------------------------------
// B2: one block per bin — LDS counting sort over 4096 keys -> ends[], csr[].
// csr entry = (src<<12) | (min(seglen,511)<<3) | rel
// ---------------------------------------------------------------------------
__global__ __launch_bounds__(256) void bin_build_kernel(const int* __restrict__ be,
                                                        const int* __restrict__ Hs,
                                                        int* __restrict__ ends,
                                                        int* __restrict__ csr,
                                                        int E, int nbins) {
    int b  = blockIdx.x;
    int s0 = Hs[b * NCHUNK];
    int s1 = (b + 1 < nbins) ? Hs[(b + 1) * NCHUNK] : E;
    int t  = threadIdx.x;

    __shared__ int cnt[KPB];
    __shared__ int off[KPB];
    __shared__ int fil[KPB];
    __shared__ int ws[4];

    for (int i = t; i < KPB; i += 256) { cnt[i] = 0; fil[i] = 0; }
    __syncthreads();

    for (int p = s0 + t; p < s1; p += 256)
        atomicAdd(&cnt[be[p] >> 17], 1);          // key = (localdst<<3)|rel
    __syncthreads();

    int kbase = t * 16;
    int loc[16];
    int sum = 0;
#pragma unroll
    for (int i = 0; i < 16; ++i) { loc[i] = sum; sum += cnt[kbase + i]; }

    int lane = t & 63, wid = t >> 6;
    int v = sum;
#pragma unroll
    for (int o = 1; o < 64; o <<= 1) {
        int u = __shfl_up(v, o, 64);
        if (lane >= o) v += u;
    }
    if (lane == 63) ws[wid] = v;
    __syncthreads();
    int woff = 0;
    for (int i = 0; i < wid; ++i) woff += ws[i];
    int excl = woff + (v - sum);
#pragma unroll
    for (int i = 0; i < 16; ++i) off[kbase + i] = excl + loc[i];
    __syncthreads();

    for (int i = t; i < KPB; i += 256)
        ends[b * KPB + i] = s0 + off[i] + cnt[i];

    for (int p = s0 + t; p < s1; p += 256) {
        int pk = be[p];
        int k  = pk >> 17;
        int slot = s0 + off[k] + atomicAdd(&fil[k], 1);
        int len  = cnt[k]; if (len > 511) len = 511;
        csr[slot] = ((pk & 0x1FFFF) << 12) | (len << 3) | (k & 7);
    }
}

// ---------------------------------------------------------------------------
// xw: xW16[n][r][c] = bf16( x[n] @ W1[r][:,c] )
// ---------------------------------------------------------------------------
#define XW_TILE 64
__global__ __launch_bounds__(256) void xw_kernel(const float* __restrict__ x,
                                                 const float* __restrict__ W1,
                                                 unsigned short* __restrict__ xW16, int N) {
    __shared__ float sx[XW_TILE * IN_CH];   // 4 KB
    int t = threadIdx.x;
    int node0 = blockIdx.x * XW_TILE;

    {
        int i4 = node0 * 4 + t;
        float4 v = make_float4(0.f, 0.f, 0.f, 0.f);
        if (i4 < N * 4) v = ((const float4*)x)[i4];
        ((float4*)sx)[t] = v;
    }
    __syncthreads();

    int r = t >> 5, c = t & 31;
    float w[IN_CH];
#pragma unroll
    for (int f = 0; f < IN_CH; ++f)
        w[f] = W1[(r * IN_CH + f) * HID_CH + c];

    int lim = N - node0; if (lim > XW_TILE) lim = XW_TILE;
    for (int ni = 0; ni < lim; ++ni) {
        const float4* xs = (const float4*)(sx + ni * IN_CH);
        float4 v0 = xs[0], v1 = xs[1], v2 = xs[2], v3 = xs[3];
        float a;
        a  = v0.x * w[0]  + v0.y * w[1]  + v0.z * w[2]  + v0.w * w[3];
        a += v1.x * w[4]  + v1.y * w[5]  + v1.z * w[6]  + v1.w * w[7];
        a += v2.x * w[8]  + v2.y * w[9]  + v2.z * w[10] + v2.w * w[11];
        a += v3.x * w[12] + v3.y * w[13] + v3.z * w[14] + v3.w * w[15];
        xW16[(node0 + ni) * (N_REL * HID_CH) + t] = f2b(a);
    }
}

// ---------------------------------------------------------------------------
// Shared epilogue: half-wave holds h[n][0..31] (one value per lane).
// Compute hW16[n][r] (r<8) and hroot[n] via broadcast-shfl over channels,
// weights staged in LDS as [f][9] (lanes 0-8 distinct banks, 9-31 broadcast).
// ---------------------------------------------------------------------------
#define EPILOGUE(swA, swB, hval, node, c, hW16, hroot, b2)                     \
    {                                                                          \
        int jj = (c < 8) ? c : 8;                                              \
        float o0 = 0.0f, o1 = 0.0f;                                            \
        _Pragma("unroll")                                                      \
        for (int f = 0; f < 32; ++f) {                                         \
            float hf = __shfl(hval, f, 32);                                    \
            o0 = fmaf(hf, swA[f * 9 + jj], o0);                                \
            o1 = fmaf(hf, swB[f * 9 + jj], o1);                                \
        }                                                                      \
        if (c < 8) {                                                           \
            hW16[((node) << 3) + c] = ((unsigned)f2b(o1) << 16) | f2b(o0);     \
        } else if (c == 8) {                                                   \
            *(float2*)(hroot + ((long)(node) << 1)) =                          \
                make_float2(o0 + b2[0], o1 + b2[1]);                           \
        }                                                                      \
    }

// ---------------------------------------------------------------------------
// l1 fused: half-wave per node, lane = channel c. FLAT 8-deep edge loop over
// the node's ~16 edges (per-edge norm from LDS 1/len table), then root term,
// relu, and the fused layer-2 transform epilogue (replaces hw_kernel + h buf).
// ---------------------------------------------------------------------------
__global__ __launch_bounds__(256) void l1_fused_kernel(const float* __restrict__ x,
                                                       const int* __restrict__ csr,
                                                       const int* __restrict__ ends,
                                                       const unsigned short* __restrict__ xW16,
                                                       const float* __restrict__ root1,
                                                       const float* __restrict__ b1,
                                                       const float* __restrict__ W2,
                                                       const float* __restrict__ root2,
                                                       const float* __restrict__ b2,
                                                       unsigned int* __restrict__ hW16,
                                                       float* __restrict__ hroot, int N) {
    __shared__ float itab[512];          // 1/len table
    __shared__ float swA[32 * 9];        // W2T + root2, output 0
    __shared__ float swB[32 * 9];        // W2T + root2, output 1
    {
        int t = threadIdx.x;
        for (int i = t; i < 512; i += 256) itab[i] = (i > 0) ? 1.0f / (float)i : 0.0f;
        for (int i = t; i < 288; i += 256) {
            int f = i / 9, j = i - f * 9;
            float a, bb;
            if (j < 8) { a = W2[(j * HID_CH + f) * 2]; bb = W2[(j * HID_CH + f) * 2 + 1]; }
            else       { a = root2[f * 2];             bb = root2[f * 2 + 1]; }
            swA[i] = a; swB[i] = bb;
        }
    }
    __syncthreads();

    int gid  = blockIdx.x * 256 + threadIdx.x;
    int node = gid >> 5;
    int c    = gid & 31;
    if (node >= N) return;

    int p0 = (node > 0) ? __ldg(&ends[node * N_REL - 1]) : 0;
    int p1 = __ldg(&ends[node * N_REL + N_REL - 1]);

    float acc = 0.0f;
    int p = p0;
    for (; p + 7 < p1; p += 8) {          // 8 independent edge chains
        int v0 = csr[p],     v1 = csr[p + 1], v2 = csr[p + 2], v3 = csr[p + 3];
        int v4 = csr[p + 4], v5 = csr[p + 5], v6 = csr[p + 6], v7 = csr[p + 7];
        float a0 = b2f(xW16[((v0 >> 12) << 8) + ((v0 & 7) << 5) + c]);
        float a1 = b2f(xW16[((v1 >> 12) << 8) + ((v1 & 7) << 5) + c]);
        float a2 = b2f(xW16[((v2 >> 12) << 8) + ((v2 & 7) << 5) + c]);
        float a3 = b2f(xW16[((v3 >> 12) << 8) + ((v3 & 7) << 5) + c]);
        float a4 = b2f(xW16[((v4 >> 12) << 8) + ((v4 & 7) << 5) + c]);
        float a5 = b2f(xW16[((v5 >> 12) << 8) + ((v5 & 7) << 5) + c]);
        float a6 = b2f(xW16[((v6 >> 12) << 8) + ((v6 & 7) << 5) + c]);
        float a7 = b2f(xW16[((v7 >> 12) << 8) + ((v7 & 7) << 5) + c]);
        acc = fmaf(a0, itab[(v0 >> 3) & 511], acc);
        acc = fmaf(a1, itab[(v1 >> 3) & 511], acc);
        acc = fmaf(a2, itab[(v2 >> 3) & 511], acc);
        acc = fmaf(a3, itab[(v3 >> 3) & 511], acc);
        acc = fmaf(a4, itab[(v4 >> 3) & 511], acc);
        acc = fmaf(a5, itab[(v5 >> 3) & 511], acc);
        acc = fmaf(a6, itab[(v6 >> 3) & 511], acc);
        acc = fmaf(a7, itab[(v7 >> 3) & 511], acc);
    }
    for (; p + 3 < p1; p += 4) {
        int v0 = csr[p], v1 = csr[p + 1], v2 = csr[p + 2], v3 = csr[p + 3];
        float a0 = b2f(xW16[((v0 >> 12) << 8) + ((v0 & 7) << 5) + c]);
        float a1 = b2f(xW16[((v1 >> 12) << 8) + ((v1 & 7) << 5) + c]);
        float a2 = b2f(xW16[((v2 >> 12) << 8) + ((v2 & 7) << 5) + c]);
        float a3 = b2f(xW16[((v3 >> 12) << 8) + ((v3 & 7) << 5) + c]);
        acc = fmaf(a0, itab[(v0 >> 3) & 511], acc);
        acc = fmaf(a1, itab[(v1 >> 3) & 511], acc);
        acc = fmaf(a2, itab[(v2 >> 3) & 511], acc);
        acc = fmaf(a3, itab[(v3 >> 3) & 511], acc);
    }
    if (p + 1 < p1) {
        int v0 = csr[p], v1 = csr[p + 1];
        float a0 = b2f(xW16[((v0 >> 12) << 8) + ((v0 & 7) << 5) + c]);
        float a1 = b2f(xW16[((v1 >> 12) << 8) + ((v1 & 7) << 5) + c]);
        acc = fmaf(a0, itab[(v0 >> 3) & 511], acc);
        acc = fmaf(a1, itab[(v1 >> 3) & 511], acc);
        p += 2;
    }
    if (p < p1) {
        int v0 = csr[p];
        acc = fmaf(b2f(xW16[((v0 >> 12) << 8) + ((v0 & 7) << 5) + c]),
                   itab[(v0 >> 3) & 511], acc);
    }

    // root term + bias + relu
    const float4* xs = (const float4*)(x + ((long)node << 4));
    float4 v0 = xs[0], v1 = xs[1], v2 = xs[2], v3 = xs[3];
    const float* wr = root1 + c;
    acc += b1[c];
    acc += v0.x * wr[0]   + v0.y * wr[32]  + v0.z * wr[64]  + v0.w * wr[96];
    acc += v1.x * wr[128] + v1.y * wr[160] + v1.z * wr[192] + v1.w * wr[224];
    acc += v2.x * wr[256] + v2.y * wr[288] + v2.z * wr[320] + v2.w * wr[352];
    acc += v3.x * wr[384] + v3.y * wr[416] + v3.z * wr[448] + v3.w * wr[480];
    float hval = fmaxf(acc, 0.0f);

    EPILOGUE(swA, swB, hval, node, c, hW16, hroot, b2)
}

// ---------------------------------------------------------------------------
// l1 fallback (no room for xW16): direct per-edge dot from LDS W1, same
// flat loop + fused epilogue.
// ---------------------------------------------------------------------------
__global__ __launch_bounds__(256) void l1_fb_kernel(const float* __restrict__ x,
                                                    const int* __restrict__ csr,
                                                    const int* __restrict__ ends,
                                                    const float* __restrict__ W1,
                                                    const float* __restrict__ root1,
                                                    const float* __restrict__ b1,
                                                    const float* __restrict__ W2,
                                                    const float* __restrict__ root2,
                                                    const float* __restrict__ b2,
                                                    unsigned int* __restrict__ hW16,
                                                    float* __restrict__ hroot, int N) {
    __shared__ float sW[N_REL * IN_CH * HID_CH];   // 16 KB
    __shared__ float itab[512];
    __shared__ float swA[32 * 9];
    __shared__ float swB[32 * 9];
    {
        int t = threadIdx.x;
        for (int i = t; i < N_REL * IN_CH * HID_CH; i += 256) sW[i] = W1[i];
        for (int i = t; i < 512; i += 256) itab[i] = (i > 0) ? 1.0f / (float)i : 0.0f;
        for (int i = t; i < 288; i += 256) {
            int f = i / 9, j = i - f * 9;
            float a, bb;
            if (j < 8) { a = W2[(j * HID_CH + f) * 2]; bb = W2[(j * HID_CH + f) * 2 + 1]; }
            else       { a = root2[f * 2];             bb = root2[f * 2 + 1]; }
            swA[i] = a; swB[i] = bb;
        }
    }
    __syncthreads();

    int gid  = blockIdx.x * 256 + threadIdx.x;
    int node = gid >> 5;
    int c    = gid & 31;
    if (node >= N) return;

    int p0 = (node > 0) ? __ldg(&ends[node * N_REL - 1]) : 0;
    int p1 = __ldg(&ends[node * N_REL + N_REL - 1]);

    float acc = 0.0f;
    for (int p = p0; p < p1; ++p) {
        int v = csr[p];
        int s = v >> 12, r = v & 7;
        const float4* xs = (const float4*)(x + ((long)s << 4));
        float4 q0 = xs[0], q1 = xs[1], q2 = xs[2], q3 = xs[3];
        const float* w = sW + ((r * IN_CH) * HID_CH) + c;
        float a;
        a  = q0.x * w[0]   + q0.y * w[32]  + q0.z * w[64]  + q0.w * w[96];
        a += q1.x * w[128] + q1.y * w[160] + q1.z * w[192] + q1.w * w[224];
        a += q2.x * w[256] + q2.y * w[288] + q2.z * w[320] + q2.w * w[352];
        a += q3.x * w[384] + q3.y * w[416] + q3.z * w[448] + q3.w * w[480];
        acc = fmaf(a, itab[(v >> 3) & 511], acc);
    }

    const float4* xs = (const float4*)(x + ((long)node << 4));
    float4 v0 = xs[0], v1 = xs[1], v2 = xs[2], v3 = xs[3];
    const float* wr = root1 + c;
    acc += b1[c];
    acc += v0.x * wr[0]   + v0.y * wr[32]  + v0.z * wr[64]  + v0.w * wr[96];
    acc += v1.x * wr[128] + v1.y * wr[160] + v1.z * wr[192] + v1.w * wr[224];
    acc += v2.x * wr[256] + v2.y * wr[288] + v2.z * wr[320] + v2.w * wr[352];
    acc += v3.x * wr[384] + v3.y * wr[416] + v3.z * wr[448] + v3.w * wr[480];
    float hval = fmaxf(acc, 0.0f);

    EPILOGUE(swA, swB, hval, node, c, hW16, hroot, b2)
}

// ---------------------------------------------------------------------------
// l2 finish: 8 lanes per node, lane = relation; 4B gathers from L2-resident
// hW16 table, 2-deep; shuffle-reduce + log_softmax.
// ---------------------------------------------------------------------------
__global__ __launch_bounds__(256) void l2_finish_kernel(const int* __restrict__ csr,
                                                        const int* __restrict__ ends,
                                                        const unsigned int* __restrict__ hW16,
                                                        const float* __restrict__ hroot,
                                                        float* __restrict__ out, int N) {
    int gid  = blockIdx.x * 256 + threadIdx.x;
    int node = gid >> 3;
    int r    = gid & 7;
    if (node >= N) return;

    int idx  = node * N_REL + r;
    int prev = (idx > 0) ? ends[idx - 1] : 0;
    int end  = ends[idx];

    float o0 = 0.0f, o1 = 0.0f;
    if (end > prev) {
        float s0 = 0.0f, s1 = 0.0f;
        int p = prev;
        for (; p + 1 < end; p += 2) {
            int a = csr[p] >> 12, b = csr[p + 1] >> 12;
            unsigned va = hW16[(a << 3) + r];
            unsigned vb = hW16[(b << 3) + r];
            s0 += b2f((unsigned short)va) + b2f((unsigned short)vb);
            s1 += b2f((unsigned short)(va >> 16)) + b2f((unsigned short)(vb >> 16));
        }
        if (p < end) {
            unsigned va = hW16[((csr[p] >> 12) << 3) + r];
            s0 += b2f((unsigned short)va);
            s1 += b2f((unsigned short)(va >> 16));
        }
        float inv = 1.0f / (float)(end - prev);
        o0 = s0 * inv; o1 = s1 * inv;
    }

#pragma unroll
    for (int m = 1; m < 8; m <<= 1) {
        o0 += __shfl_xor(o0, m, 64);
        o1 += __shfl_xor(o1, m, 64);
    }

    if (r == 0) {
        float2 rt = *(const float2*)(hroot + ((long)node << 1));
        o0 += rt.x; o1 += rt.y;
        float mx = fmaxf(o0, o1);
        float l  = mx + logf(__expf(o0 - mx) + __expf(o1 - mx));
        *(float2*)(out + ((long)node << 1)) = make_float2(o0 - l, o1 - l);
    }
}

// ---------------------------------------------------------------------------
extern "C" void kernel_launch(void* const* d_in, const int* in_sizes, int n_in,
                              void* d_out, int out_size, void* d_ws, size_t ws_size,
                              hipStream_t stream) {
    const float* x     = (const float*)d_in[0];
    const int*   eidx  = (const int*)d_in[1];
    const int*   etype = (const int*)d_in[2];
    const float* W1    = (const float*)d_in[3];
    const float* root1 = (const float*)d_in[4];
    const float* b1    = (const float*)d_in[5];
    const float* W2    = (const float*)d_in[6];
    const float* root2 = (const float*)d_in[7];
    const float* b2    = (const float*)d_in[8];
    float* out = (float*)d_out;

    const int N = in_sizes[0] / IN_CH;
    const int E = in_sizes[2];
    const int nbins   = (N + BIN_NODES - 1) >> BIN_BITS;
    const int chunksz = (E + NCHUNK - 1) / NCHUNK;
    const int M2      = nbins * NCHUNK;
    const int* src = eidx;
    const int* dst = eidx + E;

    char* wp = (char*)d_ws;
    auto take = [&](size_t bytes) {
        char* p = wp;
        wp += (bytes + 63) & ~(size_t)63;
        return p;
    };
    int*   H      = (int*)take((size_t)M2 * sizeof(int));
    int*   blksum = (int*)take(4096 * sizeof(int));
    int*   ends   = (int*)take((size_t)nbins * KPB * sizeof(int));
    int*   csr    = (int*)take((size_t)E * sizeof(int));
    int*   be     = (int*)take((size_t)E * sizeof(int));
    unsigned int* hW16 = (unsigned int*)take((size_t)N * N_REL * sizeof(unsigned int));
    float* hroot  = (float*)take((size_t)N * 2 * sizeof(float));
    unsigned short* xW16 = (unsigned short*)take((size_t)N * N_REL * HID_CH * sizeof(unsigned short));
    bool use_xw = ((size_t)(wp - (char*)d_ws) <= ws_size);

    const int B = 256;
    const int nb = (M2 + 1023) / 1024;

    part_hist_kernel<<<NCHUNK, B, 0, stream>>>(dst, H, E, nbins, chunksz);
    scan_a_kernel<<<nb, 1024, 0, stream>>>(H, blksum, M2);
    scan_b_kernel<<<1, 64, 0, stream>>>(blksum, nb);
    scan_c_kernel<<<nb, 1024, 0, stream>>>(H, blksum, M2);
    part_scatter_kernel<<<NCHUNK, B, 0, stream>>>(src, dst, etype, H, be, E, nbins, chunksz);
    bin_build_kernel<<<nbins, B, 0, stream>>>(be, H, ends, csr, E, nbins);

    if (use_xw) {
        xw_kernel<<<(N + XW_TILE - 1) / XW_TILE, B, 0, stream>>>(x, W1, xW16, N);
        l1_fused_kernel<<<(N * 32 + B - 1) / B, B, 0, stream>>>(
            x, csr, ends, xW16, root1, b1, W2, root2, b2, hW16, hroot, N);
    } else {
        l1_fb_kernel<<<(N * 32 + B - 1) / B, B, 0, stream>>>(
            x, csr, ends, W1, root1, b1, W2, root2, b2, hW16, hroot, N);
    }

    l2_finish_kernel<<<(N * 8 + B - 1) / B, B, 0, stream>>>(csr, ends, hW16, hroot, out, N);
}